// Round 1
// baseline (317.240 us; speedup 1.0000x reference)
//
#include <hip/hip_runtime.h>
#include <math.h>

#define D_MODEL 4096
#define NEXP    64
#define NTOK    16384          // 4 * 4096
#define BT      256            // tokens per block (kernel 1)
#define DC      32             // K-chunk staged in LDS
#define PAD     36             // DC + 4, conflict-free stride
#define KSPLIT  16
#define KQ      (D_MODEL / KSPLIT)   // 256

// ---------------------------------------------------------------------------
// Kernel 1: partial GEMM  logits[t][e] += sum_{d in K-slice} x[t][d]*W[e][d]
// Accumulates via fp32 atomics into a pre-zeroed [NTOK][NEXP] buffer
// (we use the combine region of d_out as that buffer; no bias here).
// ---------------------------------------------------------------------------
__global__ __launch_bounds__(256, 3)
void k1_partial_gemm(const float* __restrict__ x, const float* __restrict__ W,
                     float* logits) {
    __shared__ __align__(16) float xs[BT * PAD];    // 36 KiB
    __shared__ __align__(16) float ws[NEXP * PAD];  //  9 KiB
    const int tile = blockIdx.x;        // 0..63  (token tile)
    const int kq   = blockIdx.y;        // 0..15  (K slice)
    const int t0   = tile * BT;
    const int d0   = kq * KQ;
    const int tid  = threadIdx.x;
    const int tx   = tid & 7;           // expert group (8 experts, stride 8)
    const int ty   = tid >> 3;          // token group  (8 tokens, stride 32)

    float acc[8][8];
#pragma unroll
    for (int i = 0; i < 8; ++i)
#pragma unroll
        for (int j = 0; j < 8; ++j) acc[i][j] = 0.f;

    for (int ch = 0; ch < KQ / DC; ++ch) {
        const int dc = d0 + ch * DC;
        // stage x tile: 256 x 32 floats (2048 float4, 8 per thread), row-major
#pragma unroll
        for (int k = 0; k < 8; ++k) {
            int p   = tid + k * 256;
            int row = p >> 3;
            int col = (p & 7) << 2;
            float4 v = *reinterpret_cast<const float4*>(
                &x[(size_t)(t0 + row) * D_MODEL + dc + col]);
            *reinterpret_cast<float4*>(&xs[row * PAD + col]) = v;
        }
        // stage W tile: 64 x 32 floats (512 float4, 2 per thread)
#pragma unroll
        for (int k = 0; k < 2; ++k) {
            int p   = tid + k * 256;
            int row = p >> 3;
            int col = (p & 7) << 2;
            float4 v = *reinterpret_cast<const float4*>(
                &W[(size_t)row * D_MODEL + dc + col]);
            *reinterpret_cast<float4*>(&ws[row * PAD + col]) = v;
        }
        __syncthreads();
#pragma unroll
        for (int dd = 0; dd < DC; dd += 4) {
            float4 xv[8], wv[8];
#pragma unroll
            for (int i = 0; i < 8; ++i)
                xv[i] = *reinterpret_cast<const float4*>(
                    &xs[(ty + (i << 5)) * PAD + dd]);
#pragma unroll
            for (int j = 0; j < 8; ++j)
                wv[j] = *reinterpret_cast<const float4*>(
                    &ws[(tx + (j << 3)) * PAD + dd]);
#pragma unroll
            for (int i = 0; i < 8; ++i)
#pragma unroll
                for (int j = 0; j < 8; ++j) {
                    acc[i][j] += xv[i].x * wv[j].x;
                    acc[i][j] += xv[i].y * wv[j].y;
                    acc[i][j] += xv[i].z * wv[j].z;
                    acc[i][j] += xv[i].w * wv[j].w;
                }
        }
        __syncthreads();
    }
    // accumulate partial logits (16 K-slices contend lightly per address)
#pragma unroll
    for (int i = 0; i < 8; ++i) {
        int t = t0 + ty + (i << 5);
#pragma unroll
        for (int j = 0; j < 8; ++j)
            atomicAdd(&logits[(size_t)t * NEXP + tx + (j << 3)], acc[i][j]);
    }
}

// ---------------------------------------------------------------------------
// Kernel 2: per-token bias + softmax + top-2 + dense scatter + expert counts.
// logits aliases the combine region of out; each thread reads then rewrites
// only its own row.
// ---------------------------------------------------------------------------
__global__ __launch_bounds__(256)
void k2_softmax_top2(const float* logits, const float* __restrict__ bias,
                     float* out) {
    const int t = blockIdx.x * 256 + threadIdx.x;   // 0..16383
    __shared__ float cnt[NEXP];
    __shared__ float bs[NEXP];
    if (threadIdx.x < NEXP) {
        cnt[threadIdx.x] = 0.f;
        bs[threadIdx.x]  = bias[threadIdx.x];
    }
    __syncthreads();

    float l[NEXP];
    const float* lp = logits + (size_t)t * NEXP;
#pragma unroll
    for (int g = 0; g < 16; ++g) {
        float4 v = *reinterpret_cast<const float4*>(&lp[g * 4]);
        l[4 * g + 0] = v.x + bs[4 * g + 0];
        l[4 * g + 1] = v.y + bs[4 * g + 1];
        l[4 * g + 2] = v.z + bs[4 * g + 2];
        l[4 * g + 3] = v.w + bs[4 * g + 3];
    }

    float m = l[0];
#pragma unroll
    for (int e = 1; e < NEXP; ++e) m = fmaxf(m, l[e]);

    float sum = 0.f;
#pragma unroll
    for (int e = 0; e < NEXP; ++e) sum += __expf(l[e] - m);

    // top-2 scan; strict '>' keeps the lower index on ties (matches top_k)
    float v1 = -INFINITY, v2 = -INFINITY;
    int   i1 = 0, i2 = 0;
#pragma unroll
    for (int e = 0; e < NEXP; ++e) {
        if (l[e] > v1) { v2 = v1; i2 = i1; v1 = l[e]; i1 = e; }
        else if (l[e] > v2) { v2 = l[e]; i2 = e; }
    }
    const float inv = 1.f / sum;
    const float s1 = __expf(v1 - m) * inv;
    const float s2 = __expf(v2 - m) * inv;

    float* disp = out + (size_t)t * NEXP;
    float* comb = out + (size_t)NTOK * NEXP + (size_t)t * NEXP;
#pragma unroll
    for (int g = 0; g < 16; ++g) {
        float4 o = make_float4(0.f, 0.f, 0.f, 0.f);
        if ((i1 >> 2) == g) (&o.x)[i1 & 3] = s1;
        if ((i2 >> 2) == g) (&o.x)[i2 & 3] = s2;
        *reinterpret_cast<float4*>(&disp[g * 4]) = o;
        *reinterpret_cast<float4*>(&comb[g * 4]) = o;
    }

    atomicAdd(&cnt[i1], s1);
    atomicAdd(&cnt[i2], s2);
    __syncthreads();
    if (threadIdx.x < NEXP)
        atomicAdd(&out[(size_t)2 * NTOK * NEXP + threadIdx.x], cnt[threadIdx.x]);
}

// ---------------------------------------------------------------------------
extern "C" void kernel_launch(void* const* d_in, const int* in_sizes, int n_in,
                              void* d_out, int out_size, void* d_ws, size_t ws_size,
                              hipStream_t stream) {
    const float* x = (const float*)d_in[0];
    const float* W = (const float*)d_in[1];
    const float* b = (const float*)d_in[2];
    float* out = (float*)d_out;

    float* logits = out + (size_t)NTOK * NEXP;  // combine region doubles as logit accumulator

    // zero combine region (logit accumulator) + expert_counts tail
    hipMemsetAsync(logits, 0, ((size_t)NTOK * NEXP + NEXP) * sizeof(float), stream);

    dim3 g1(NTOK / BT, KSPLIT);   // 64 x 16
    k1_partial_gemm<<<g1, 256, 0, stream>>>(x, W, logits);

    k2_softmax_top2<<<NTOK / 256, 256, 0, stream>>>(logits, b, out);
}

// Round 2
// 160.174 us; speedup vs baseline: 1.9806x; 1.9806x over previous
//
#include <hip/hip_runtime.h>
#include <math.h>

#define D_MODEL 4096
#define NEXP    64
#define NTOK    16384
#define BT      32                 // tokens per block
#define BK      64                 // K per step
#define NSTEP   (D_MODEL / BK)     // 64
#define LGSTR   72                 // logits LDS stride (pad)

typedef __attribute__((ext_vector_type(8))) short  bf16x8;
typedef __attribute__((ext_vector_type(4))) float  f32x4;

__device__ __forceinline__ unsigned short f2bf_rn(float f) {
    union { float f; unsigned u; } v; v.f = f;
    unsigned r = v.u + 0x7fffu + ((v.u >> 16) & 1u);
    return (unsigned short)(r >> 16);
}
__device__ __forceinline__ float bf2f(unsigned short h) {
    union { unsigned u; float f; } v; v.u = ((unsigned)h) << 16;
    return v.f;
}

// (v,i) pair merge keeping jax.lax.top_k semantics (lower index wins ties)
__device__ __forceinline__ void top2_merge(float& v1, int& i1, float& v2, int& i2,
                                           float ov1, int oi1, float ov2, int oi2) {
    if (ov1 > v1 || (ov1 == v1 && oi1 < i1)) {
        float nv2 = v1; int ni2 = i1;
        if (ov2 > nv2 || (ov2 == nv2 && oi2 < ni2)) { nv2 = ov2; ni2 = oi2; }
        v1 = ov1; i1 = oi1; v2 = nv2; i2 = ni2;
    } else {
        if (ov1 > v2 || (ov1 == v2 && oi1 < i2)) { v2 = ov1; i2 = oi1; }
    }
}

// ---------------------------------------------------------------------------
// k0: split W (f32 [64][4096]) into bf16 hi/lo halves in ws.
// ---------------------------------------------------------------------------
__global__ __launch_bounds__(256)
void k0_split_w(const float* __restrict__ W, unsigned short* __restrict__ ws) {
    int i = (blockIdx.x * 256 + threadIdx.x) * 4;      // 65536 threads x 4 elems
    float4 v = *reinterpret_cast<const float4*>(&W[i]);
    unsigned short h[4], l[4];
    float f[4] = {v.x, v.y, v.z, v.w};
#pragma unroll
    for (int k = 0; k < 4; ++k) {
        h[k] = f2bf_rn(f[k]);
        l[k] = f2bf_rn(f[k] - bf2f(h[k]));
    }
    *reinterpret_cast<short4*>(&ws[i])                     = make_short4(h[0], h[1], h[2], h[3]);
    *reinterpret_cast<short4*>(&ws[NEXP * D_MODEL + i])    = make_short4(l[0], l[1], l[2], l[3]);
}

// ---------------------------------------------------------------------------
// k1: fused  logits = x Wh^T/Wl^T (bf16-split MFMA)  -> softmax -> top2 ->
// dense dispatch/combine + expert counts.  Block: 32 tokens x 64 experts,
// full K. 8 waves: wave w -> Mtile (w>>2), expert strip 16*(w&3).
// ---------------------------------------------------------------------------
__global__ __launch_bounds__(512, 4)
void k1_fused(const float* __restrict__ x, const unsigned short* __restrict__ wsplit,
              const float* __restrict__ bias, float* __restrict__ out) {
    __shared__ __align__(16) float xs[2][BT * BK];   // 2 x 8 KiB
    __shared__ float cnt[NEXP];

    const int tid  = threadIdx.x;
    const int t0   = blockIdx.x * BT;
    const int w    = tid >> 6;
    const int lane = tid & 63;
    const int m    = w >> 2;            // Mtile (0/1)
    const int n    = w & 3;             // expert strip
    const int rowl = lane & 15;
    const int grp  = lane >> 4;         // 0..3

    if (tid < NEXP) cnt[tid] = 0.f;

    const unsigned short* Whi = wsplit;
    const unsigned short* Wlo = wsplit + NEXP * D_MODEL;

    // staging geometry: thread tid stages LDS slot s=tid (16B); source chunk
    // column is XOR-swizzled so swizzled ds_reads are conflict-free (G21).
    const int s_tok = tid >> 4;
    const int s_kc  = (tid & 15) ^ (s_tok & 7);
    const float* gsrc_base = x + (size_t)(t0 + s_tok) * D_MODEL + s_kc * 4;

    // A-fragment read geometry (swizzled)
    const int a_tok   = m * 16 + rowl;
    const int a_base  = a_tok * 16;     // 16B-slot row base
    const int a_swz   = a_tok & 7;

    // B-fragment pointers
    const int e = n * 16 + rowl;
    const unsigned short* bhp = Whi + (size_t)e * D_MODEL + grp * 8;
    const unsigned short* blp = Wlo + (size_t)e * D_MODEL + grp * 8;

    f32x4 acc = {0.f, 0.f, 0.f, 0.f};

    // prologue: stage step 0 into buf 0
    {
        char* dst = (char*)&xs[0][0] + tid * 16;
        __builtin_amdgcn_global_load_lds(
            (const __attribute__((address_space(1))) void*)gsrc_base,
            (__attribute__((address_space(3))) void*)dst, 16, 0, 0);
    }

    for (int t = 0; t < NSTEP; ++t) {
        __syncthreads();   // stage(t) landed; all waves done with buf (t&1)^1
        if (t + 1 < NSTEP) {
            char* dst = (char*)&xs[(t + 1) & 1][0] + tid * 16;
            const float* g = gsrc_base + (size_t)(t + 1) * BK;
            __builtin_amdgcn_global_load_lds(
                (const __attribute__((address_space(1))) void*)g,
                (__attribute__((address_space(3))) void*)dst, 16, 0, 0);
        }
        const float* buf = &xs[t & 1][0];
        const int kb = t * BK;
#pragma unroll
        for (int f = 0; f < 2; ++f) {
            // A: 8 consecutive f32 (2 swizzled 16B chunks) -> hi/lo bf16
            const int kc0 = f * 8 + grp * 2;
            f32x4 c0 = *reinterpret_cast<const f32x4*>(&buf[(a_base + (kc0 ^ a_swz)) * 4]);
            f32x4 c1 = *reinterpret_cast<const f32x4*>(&buf[(a_base + ((kc0 + 1) ^ a_swz)) * 4]);
            float av[8] = {c0.x, c0.y, c0.z, c0.w, c1.x, c1.y, c1.z, c1.w};
            bf16x8 ah, al;
#pragma unroll
            for (int j = 0; j < 8; ++j) {
                unsigned short h = f2bf_rn(av[j]);
                ah[j] = (short)h;
                al[j] = (short)f2bf_rn(av[j] - bf2f(h));
            }
            // B: preconverted bf16, contiguous 16B loads (L2-resident)
            bf16x8 bh = *reinterpret_cast<const bf16x8*>(&bhp[kb + f * 32]);
            bf16x8 bl = *reinterpret_cast<const bf16x8*>(&blp[kb + f * 32]);

            acc = __builtin_amdgcn_mfma_f32_16x16x32_bf16(ah, bh, acc, 0, 0, 0);
            acc = __builtin_amdgcn_mfma_f32_16x16x32_bf16(ah, bl, acc, 0, 0, 0);
            acc = __builtin_amdgcn_mfma_f32_16x16x32_bf16(al, bh, acc, 0, 0, 0);
        }
    }

    // ---- epilogue: logits tile -> LDS, fused softmax + top2 ----
    __syncthreads();                      // done reading xs
    float* lg = (float*)&xs[0][0];        // 32 x 72 f32 = 9216 B, fits
#pragma unroll
    for (int i = 0; i < 4; ++i)
        lg[(m * 16 + grp * 4 + i) * LGSTR + n * 16 + rowl] = acc[i];
    __syncthreads();

    const int token = tid >> 4;           // 0..31
    const int j     = tid & 15;           // 16 threads per token
    float4 v4 = *reinterpret_cast<const float4*>(&lg[token * LGSTR + j * 4]);
    float lv[4] = {v4.x + bias[j * 4 + 0], v4.y + bias[j * 4 + 1],
                   v4.z + bias[j * 4 + 2], v4.w + bias[j * 4 + 3]};

    // local top-2 of 4 (ascending index + strict '>' => lower index wins ties)
    float v1 = lv[0], v2 = -INFINITY;
    int   i1 = j * 4, i2 = 1 << 30;
#pragma unroll
    for (int k = 1; k < 4; ++k) {
        if (lv[k] > v1)      { v2 = v1; i2 = i1; v1 = lv[k]; i1 = j * 4 + k; }
        else if (lv[k] > v2) { v2 = lv[k]; i2 = j * 4 + k; }
    }
#pragma unroll
    for (int mask = 1; mask < 16; mask <<= 1) {
        float ov1 = __shfl_xor(v1, mask);
        int   oi1 = __shfl_xor(i1, mask);
        float ov2 = __shfl_xor(v2, mask);
        int   oi2 = __shfl_xor(i2, mask);
        top2_merge(v1, i1, v2, i2, ov1, oi1, ov2, oi2);
    }
    // v1 is the row max; sum of exp(l - v1)
    float s = 0.f;
#pragma unroll
    for (int k = 0; k < 4; ++k) s += __expf(lv[k] - v1);
#pragma unroll
    for (int mask = 1; mask < 16; mask <<= 1) s += __shfl_xor(s, mask);

    const float invS = 1.f / s;
    const float s1 = invS;                      // exp(v1 - v1) / S
    const float s2 = __expf(v2 - v1) * invS;

    const int tg = t0 + token;
    float4 o = make_float4(0.f, 0.f, 0.f, 0.f);
    if ((i1 >> 2) == j) (&o.x)[i1 & 3] = s1;
    if ((i2 >> 2) == j) (&o.x)[i2 & 3] = s2;
    *reinterpret_cast<float4*>(&out[(size_t)tg * NEXP + j * 4]) = o;
    *reinterpret_cast<float4*>(&out[(size_t)NTOK * NEXP + (size_t)tg * NEXP + j * 4]) = o;

    if (j == 0) {
        atomicAdd(&cnt[i1], s1);
        atomicAdd(&cnt[i2], s2);
    }
    __syncthreads();
    if (tid < NEXP)
        atomicAdd(&out[(size_t)2 * NTOK * NEXP + tid], cnt[tid]);
}

// ---------------------------------------------------------------------------
extern "C" void kernel_launch(void* const* d_in, const int* in_sizes, int n_in,
                              void* d_out, int out_size, void* d_ws, size_t ws_size,
                              hipStream_t stream) {
    const float* x = (const float*)d_in[0];
    const float* W = (const float*)d_in[1];
    const float* b = (const float*)d_in[2];
    float* out = (float*)d_out;
    unsigned short* ws = (unsigned short*)d_ws;   // needs 1 MiB

    // zero expert_counts tail (dispatch/combine fully overwritten each call)
    hipMemsetAsync(out + (size_t)2 * NTOK * NEXP, 0, NEXP * sizeof(float), stream);

    k0_split_w<<<NEXP * D_MODEL / (256 * 4), 256, 0, stream>>>(W, ws);
    k1_fused<<<NTOK / BT, 512, 0, stream>>>(x, ws, b, out);
}